// Round 13
// baseline (2641.128 us; speedup 1.0000x reference)
//
#include <hip/hip_runtime.h>

typedef __bf16 bf16x8 __attribute__((ext_vector_type(8)));
typedef float f32x4 __attribute__((ext_vector_type(4)));
typedef unsigned short ushort8_t __attribute__((ext_vector_type(8)));
typedef unsigned short ushort4_t __attribute__((ext_vector_type(4)));

#define MFMA16(a, b, c) __builtin_amdgcn_mfma_f32_16x16x32_bf16((a), (b), (c), 0, 0, 0)

#define GLOAD16(gp, lp)                                                        \
  __builtin_amdgcn_global_load_lds(                                            \
      (__attribute__((address_space(1))) void*)(gp),                           \
      (__attribute__((address_space(3))) void*)(lp), 16, 0, 0)

__device__ __forceinline__ unsigned short f2bf(float f) {
  unsigned u = __builtin_bit_cast(unsigned, f);
  return (unsigned short)((u + 0x7FFFu + ((u >> 16) & 1u)) >> 16);
}

// Tiled ("staging-order") layout for GEMM operands, [R][K] logical:
//   addr(r,k) = ((r>>4)*(K>>5) + (k>>5))*512 + ((k>>3)&3)*128 + (r&15)*8 + (k&7)
// One 16x32 tile = 512 contiguous elems = one GLOAD16; LDS linear; fragment
// ds_read_b128 at base + l*16B: conflict-free; staging fully coalesced.

// ---------------------------------------------------------------------------
__global__ __launch_bounds__(256) void transpose_f2b_tiled(
    const float* __restrict__ src, unsigned short* __restrict__ dst,
    int Kdim, int Ndim) {
  const long u = (long)blockIdx.x * 256 + threadIdx.x;  // 16B unit
  const long total = ((long)Kdim * Ndim) >> 3;
  if (u >= total) return;
  const int kt32 = Kdim >> 5;
  const long tile = u >> 6;
  const int t8 = (int)(u & 63);
  const int chunk = t8 >> 4, rowlow = t8 & 15;
  const int n = (int)(tile / kt32) * 16 + rowlow;
  const int k0 = (int)(tile % kt32) * 32 + chunk * 8;
  ushort8_t o;
#pragma unroll
  for (int e = 0; e < 8; e++) o[e] = f2bf(src[(long)(k0 + e) * Ndim + n]);
  *(ushort8_t*)(dst + (u << 3)) = o;
}

// ---------------------------------------------------------------------------
__global__ __launch_bounds__(256) void ln_kernel(
    const float* __restrict__ x, const float* __restrict__ gw,
    const float* __restrict__ gb, unsigned short* __restrict__ h) {
  const int row = blockIdx.x * 4 + (threadIdx.x >> 6);
  const int l = threadIdx.x & 63;
  const float* xr = x + (long)row * 768;
  f32x4 va[3];
#pragma unroll
  for (int i = 0; i < 3; i++) va[i] = *(const f32x4*)(xr + i * 256 + l * 4);
  float s = 0.f, ss = 0.f;
#pragma unroll
  for (int i = 0; i < 3; i++)
#pragma unroll
    for (int j = 0; j < 4; j++) {
      float t = va[i][j];
      s += t;
      ss += t * t;
    }
#pragma unroll
  for (int off = 1; off < 64; off <<= 1) {
    s += __shfl_xor(s, off, 64);
    ss += __shfl_xor(ss, off, 64);
  }
  const float mu = s * (1.f / 768.f);
  const float var = ss * (1.f / 768.f) - mu * mu;
  const float inv = rsqrtf(var + 1e-5f);
  const long tb = ((long)(row >> 4) * 24) << 9;
  const int rlow = (row & 15) * 8;
  const int coff = ((l >> 1) & 3) * 128 + rlow + (l & 1) * 4;
#pragma unroll
  for (int i = 0; i < 3; i++) {
    f32x4 wv = *(const f32x4*)(gw + i * 256 + l * 4);
    f32x4 bv = *(const f32x4*)(gb + i * 256 + l * 4);
    ushort4_t o;
#pragma unroll
    for (int j = 0; j < 4; j++) o[j] = f2bf((va[i][j] - mu) * inv * wv[j] + bv[j]);
    const long addr = tb + ((long)(i * 8 + (l >> 3)) << 9) + coff;
    *(ushort4_t*)(h + addr) = o;
  }
}

enum { EPI_QKV = 0, EPI_GELU = 1, EPI_RES = 2 };

// ---------------------------------------------------------------------------
// GEMM on TILED operands (R9/R12-proven): tile BM x 128 (BM = MREP*32),
// 4 waves, BK=64 two-plane, 2-phase dbuf, one __syncthreads per K-step.
// COLMAJOR=1: consecutive same-XCD blocks share bx (B-panel L2-resident;
// fixes the B-thrash over-fetch seen at 80 MB FETCH in R12).
template <int EPI, int MREP, int COLMAJOR>
__global__ __launch_bounds__(256) void gemm_bt(
    const unsigned short* __restrict__ A, const unsigned short* __restrict__ BT,
    int K, const float* __restrict__ bb0, const float* __restrict__ bb1,
    const float* __restrict__ bb2, unsigned short* __restrict__ o0,
    unsigned short* __restrict__ o1, unsigned short* __restrict__ o2,
    const float* oFin, float* oFout) {
  constexpr int BM = MREP * 32;
  constexpr int AG = BM / 16;  // A row-groups
  __shared__ unsigned short As[2][2][AG * 512];
  __shared__ unsigned short Bs[2][2][8 * 512];
  const int tid = threadIdx.x;
  const int w = tid >> 6, l = tid & 63;
  const int lr = l & 15, lg = l >> 4;
  const int wr = w >> 1, wc = w & 1;

  const int nx = gridDim.x;
  const int ny = gridDim.y;
  const int nwg = nx * ny;
  int wg = blockIdx.y * nx + blockIdx.x;
  {
    const int qq = nwg >> 3, rr = nwg & 7;
    const int xcd = wg & 7, idx = wg >> 3;
    wg = (xcd < rr ? xcd * (qq + 1) : rr * (qq + 1) + (xcd - rr) * qq) + idx;
  }
  int bx, by;
  if (COLMAJOR) {
    bx = wg / ny;
    by = wg - bx * ny;
  } else {
    bx = wg % nx;
    by = wg / nx;
  }
  const int m0 = by * BM, n0 = bx * 128;

  const int nk32 = K >> 5;
  const long abase = (long)(m0 >> 4) * nk32;
  const long bbase = (long)(n0 >> 4) * nk32;

  auto stage = [&](int buf, int kt) {
#pragma unroll
    for (int kk = 0; kk < 2; kk++) {
      const int pk = kt * 2 + kk;
#pragma unroll
      for (int t = 0; t < AG / 4; t++) {
        const int g = w + t * 4;
        GLOAD16(A + ((abase + (long)g * nk32 + pk) << 9) + l * 8,
                &As[buf][kk][g * 512 + l * 8]);
      }
#pragma unroll
      for (int t = 0; t < 2; t++) {
        const int g = w + t * 4;
        GLOAD16(BT + ((bbase + (long)g * nk32 + pk) << 9) + l * 8,
                &Bs[buf][kk][g * 512 + l * 8]);
      }
    }
  };

  f32x4 acc[MREP][4] = {};
  const int nk = K >> 6;
  stage(0, 0);
  for (int kt = 0; kt < nk; ++kt) {
    const int cur = kt & 1;
    __syncthreads();  // drains stage(kt), issued one full compute-step ago
    if (kt + 1 < nk) stage(cur ^ 1, kt + 1);
#pragma unroll
    for (int kk = 0; kk < 2; kk++) {
      bf16x8 a[MREP], b[4];
#pragma unroll
      for (int i = 0; i < MREP; i++)
        a[i] = *(const bf16x8*)(&As[cur][kk][(wr * MREP + i) * 512 + l * 8]);
#pragma unroll
      for (int j = 0; j < 4; j++)
        b[j] = *(const bf16x8*)(&Bs[cur][kk][(wc * 4 + j) * 512 + l * 8]);
      __builtin_amdgcn_s_setprio(1);
#pragma unroll
      for (int i = 0; i < MREP; i++)
#pragma unroll
        for (int j = 0; j < 4; j++) acc[i][j] = MFMA16(a[i], b[j], acc[i][j]);
      __builtin_amdgcn_s_setprio(0);
    }
  }

  // ----- epilogue -----
  if (EPI == EPI_QKV) {
    const int whichq = n0 / 768;
    const int cc0 = n0 - whichq * 768;
    const float* bias = whichq == 0 ? bb0 : whichq == 1 ? bb1 : bb2;
    if (whichq < 2) {
      unsigned short* dst = whichq == 0 ? o0 : o1;
#pragma unroll
      for (int i = 0; i < MREP; i++) {
        const int r = m0 + wr * MREP * 16 + i * 16 + lg * 4;
#pragma unroll
        for (int j = 0; j < 4; j++) {
          const int ccol = cc0 + wc * 64 + j * 16 + lr;
          const int hd = ccol >> 6, d = ccol & 63;
          const float bv = bias[ccol];
#pragma unroll
          for (int q = 0; q < 4; q++) {
            const int row = r + q;
            const int bidx = row >> 9, n = row & 511;
            const long addr = ((long)(bidx * 12 + hd) * 512 + n) * 64 + d;
            dst[addr] = f2bf(acc[i][j][q] + bv);
          }
        }
      }
    } else {
#pragma unroll
      for (int i = 0; i < MREP; i++) {
        const int r = m0 + wr * MREP * 16 + i * 16 + lg * 4;
        const int bidx = r >> 9, nb = r & 511;
#pragma unroll
        for (int j = 0; j < 4; j++) {
          const int ccol = cc0 + wc * 64 + j * 16 + lr;
          const int hd = ccol >> 6, d = ccol & 63;
          const float bv = bias[ccol];
          ushort4_t pk;
#pragma unroll
          for (int q = 0; q < 4; q++) pk[q] = f2bf(acc[i][j][q] + bv);
          *(ushort4_t*)(&o2[((long)(bidx * 12 + hd) * 64 + d) * 512 + nb]) = pk;
        }
      }
    }
  } else if (EPI == EPI_GELU) {
#pragma unroll
    for (int i = 0; i < MREP; i++) {
      const int r = m0 + wr * MREP * 16 + i * 16 + lg * 4;
#pragma unroll
      for (int j = 0; j < 4; j++) {
        const int c = n0 + wc * 64 + j * 16 + lr;
        const float bv = bb0[c];
        const long cpart = ((long)(c >> 5) << 9) + ((c >> 3) & 3) * 128 + (c & 7);
#pragma unroll
        for (int q = 0; q < 4; q++) {
          const int row = r + q;
          float v = acc[i][j][q] + bv;
          const float u = v * (0.7978845608f + 0.0356774081f * v * v);
          const float g = v / (1.0f + __expf(-2.0f * u));
          o0[(((long)(row >> 4) * 96) << 9) + cpart + (row & 15) * 8] = f2bf(g);
        }
      }
    }
  } else {
#pragma unroll
    for (int i = 0; i < MREP; i++) {
      const int r = m0 + wr * MREP * 16 + i * 16 + lg * 4;
#pragma unroll
      for (int j = 0; j < 4; j++) {
        const int c = n0 + wc * 64 + j * 16 + lr;
        const float bv = bb0[c];
#pragma unroll
        for (int q = 0; q < 4; q++) {
          const long addr = (long)(r + q) * 768 + c;
          oFout[addr] = acc[i][j][q] + bv + oFin[addr];
        }
      }
    }
  }
}

// ---------------------------------------------------------------------------
// Flash attention (R7-proven, unchanged).
__global__ __launch_bounds__(256) void attn_kernel(
    const unsigned short* __restrict__ qg, const unsigned short* __restrict__ kg,
    const unsigned short* __restrict__ vtg, float* __restrict__ x) {
  __shared__ unsigned short Sh[128 * 64];
  __shared__ unsigned short Ks[2][64 * 64];
  __shared__ unsigned short Vt[2][64 * 64];
  const int qt = blockIdx.x, h = blockIdx.y, b = blockIdx.z;
  const int bh = b * 12 + h;
  const int tid = threadIdx.x, w = tid >> 6, l = tid & 63;
  const int lr = l & 15, lg = l >> 4;
  const int fchunk = ((l & 7) ^ ((l >> 3) & 7)) * 8;
  const int rk = lr & 7;

  const unsigned short* qbase =
      qg + ((long)bh * 512 + qt * 128 + w * 32 + (l >> 3)) * 64 + fchunk;
  unsigned short* shW = &Sh[w * 2048 + l * 8];
#pragma unroll
  for (int cc = 0; cc < 4; cc++) GLOAD16(qbase + cc * 8 * 64, shW + cc * 512);

  const unsigned short* kbase =
      kg + ((long)bh * 512 + w * 16 + (l >> 3)) * 64 + fchunk;
  const unsigned short* vbase =
      vtg + ((long)bh * 64 + w * 16 + (l >> 3)) * 512 + fchunk;
  unsigned short* KsW = &Ks[0][w * 1024 + l * 8];
  unsigned short* VtW = &Vt[0][w * 1024 + l * 8];

  auto stageKV = [&](int buf, int kt) {
#pragma unroll
    for (int cc = 0; cc < 2; cc++) {
      GLOAD16(kbase + (kt * 64 + cc * 8) * 64, KsW + buf * 4096 + cc * 512);
      GLOAD16(vbase + cc * 8 * 512 + kt * 64, VtW + buf * 4096 + cc * 512);
    }
  };
  stageKV(0, 0);
  __syncthreads();

  bf16x8 qa[2][2];
#pragma unroll
  for (int mi = 0; mi < 2; mi++)
#pragma unroll
    for (int ds = 0; ds < 2; ds++) {
      qa[mi][ds] = *(const bf16x8*)(&Sh[(w * 32 + mi * 16 + lr) * 64 +
                                        ((ds * 4 + lg) ^ rk) * 8]);
#pragma unroll
      for (int e = 0; e < 8; e++)
        qa[mi][ds][e] = (__bf16)(0.125f * (float)qa[mi][ds][e]);
    }

  unsigned short* Pw = &Sh[w * 2048];
  float lsum[8] = {};
  f32x4 o[2][4] = {};

  for (int kt = 0; kt < 8; ++kt) {
    const int cur = kt & 1;
    if (kt < 7) stageKV(cur ^ 1, kt + 1);

    f32x4 s[2][4] = {};
#pragma unroll
    for (int ds = 0; ds < 2; ++ds) {
      bf16x8 kb[4];
#pragma unroll
      for (int nj = 0; nj < 4; nj++)
        kb[nj] = *(const bf16x8*)(&Ks[cur][(nj * 16 + lr) * 64 +
                                           ((ds * 4 + lg) ^ rk) * 8]);
#pragma unroll
      for (int mi = 0; mi < 2; mi++)
#pragma unroll
        for (int nj = 0; nj < 4; nj++) s[mi][nj] = MFMA16(qa[mi][ds], kb[nj], s[mi][nj]);
    }

#pragma unroll
    for (int mi = 0; mi < 2; mi++)
#pragma unroll
      for (int nj = 0; nj < 4; nj++) {
        const int cL = nj * 2 + (lr >> 3);
#pragma unroll
        for (int q = 0; q < 4; q++) {
          const int row = mi * 16 + lg * 4 + q;
          const float p = __expf(s[mi][nj][q]);
          lsum[mi * 4 + q] += p;
          Pw[row * 64 + ((cL ^ (row & 7)) * 8) + (lr & 7)] = f2bf(p);
        }
      }

#pragma unroll
    for (int ks = 0; ks < 2; ++ks) {
      bf16x8 pa[2], vb[4];
#pragma unroll
      for (int mi = 0; mi < 2; mi++)
        pa[mi] = *(const bf16x8*)(&Pw[(mi * 16 + lr) * 64 +
                                      ((ks * 4 + lg) ^ rk) * 8]);
#pragma unroll
      for (int dj = 0; dj < 4; dj++)
        vb[dj] = *(const bf16x8*)(&Vt[cur][(dj * 16 + lr) * 64 +
                                           ((ks * 4 + lg) ^ rk) * 8]);
#pragma unroll
      for (int mi = 0; mi < 2; mi++)
#pragma unroll
        for (int dj = 0; dj < 4; dj++) o[mi][dj] = MFMA16(pa[mi], vb[dj], o[mi][dj]);
    }
    __syncthreads();
  }

#pragma unroll
  for (int i = 0; i < 8; i++) {
#pragma unroll
    for (int off = 1; off < 16; off <<= 1) lsum[i] += __shfl_xor(lsum[i], off, 64);
  }

#pragma unroll
  for (int mi = 0; mi < 2; mi++) {
#pragma unroll
    for (int q = 0; q < 4; q++) {
      const int n = qt * 128 + w * 32 + mi * 16 + lg * 4 + q;
      const float inv = 1.0f / lsum[mi * 4 + q];
      const long base = ((long)(b * 512 + n)) * 768 + h * 64;
#pragma unroll
      for (int dj = 0; dj < 4; dj++) {
        const long a = base + dj * 16 + lr;
        x[a] = x[a] + o[mi][dj][q] * inv;
      }
    }
  }
}

// ---------------------------------------------------------------------------
extern "C" void kernel_launch(void* const* d_in, const int* in_sizes, int n_in,
                              void* d_out, int out_size, void* d_ws,
                              size_t ws_size, hipStream_t stream) {
  const float* x_in = (const float*)d_in[0];
  const float* ln_w = (const float*)d_in[1];
  const float* ln_b = (const float*)d_in[2];
  const float* wq = (const float*)d_in[3];
  const float* bq = (const float*)d_in[4];
  const float* wk = (const float*)d_in[5];
  const float* bk = (const float*)d_in[6];
  const float* wv = (const float*)d_in[7];
  const float* bv = (const float*)d_in[8];
  const float* w1 = (const float*)d_in[9];
  const float* b1 = (const float*)d_in[10];
  const float* w2 = (const float*)d_in[11];
  const float* b2 = (const float*)d_in[12];

  char* p = (char*)d_ws;
  float* xw = (float*)p;            p += 8192L * 768 * 4;
  unsigned short* hbuf = (unsigned short*)p;  p += 8192L * 768 * 2;
  unsigned short* wqkvT = (unsigned short*)p; p += 2304L * 768 * 2;
  unsigned short* w1T = (unsigned short*)p;   p += 3072L * 768 * 2;
  unsigned short* w2T = (unsigned short*)p;   p += 768L * 3072 * 2;
  unsigned short* qb = (unsigned short*)p;
  unsigned short* kb = qb + 6291456L;
  unsigned short* vt = kb + 6291456L;
  unsigned short* gbuf = qb;  // MLP hidden reuses q/k/v region

  hipMemcpyAsync(xw, x_in, 8192L * 768 * 4, hipMemcpyDeviceToDevice, stream);

  transpose_f2b_tiled<<<(768 * 768 / 8 + 255) / 256, 256, 0, stream>>>(
      wq, wqkvT, 768, 768);
  transpose_f2b_tiled<<<(768 * 768 / 8 + 255) / 256, 256, 0, stream>>>(
      wk, wqkvT + 768L * 768, 768, 768);
  transpose_f2b_tiled<<<(768 * 768 / 8 + 255) / 256, 256, 0, stream>>>(
      wv, wqkvT + 2L * 768 * 768, 768, 768);
  transpose_f2b_tiled<<<(768 * 3072 / 8 + 255) / 256, 256, 0, stream>>>(
      w1, w1T, 768, 3072);
  transpose_f2b_tiled<<<(768 * 3072 / 8 + 255) / 256, 256, 0, stream>>>(
      w2, w2T, 3072, 768);

  for (int layer = 0; layer < 12; ++layer) {
    ln_kernel<<<2048, 256, 0, stream>>>(xw, ln_w, ln_b, hbuf);
    gemm_bt<EPI_QKV, 2, 1><<<dim3(18, 128), 256, 0, stream>>>(
        hbuf, wqkvT, 768, bq, bk, bv, qb, kb, vt, nullptr, nullptr);
    attn_kernel<<<dim3(4, 12, 16), 256, 0, stream>>>(qb, kb, vt, xw);
    ln_kernel<<<2048, 256, 0, stream>>>(xw, ln_w, ln_b, hbuf);
    gemm_bt<EPI_GELU, 2, 1><<<dim3(24, 128), 256, 0, stream>>>(
        hbuf, w1T, 768, b1, nullptr, nullptr, gbuf, nullptr, nullptr, nullptr,
        nullptr);
    gemm_bt<EPI_RES, 2, 0><<<dim3(6, 128), 256, 0, stream>>>(
        gbuf, w2T, 3072, b2, nullptr, nullptr, nullptr, nullptr, nullptr, xw,
        layer == 11 ? (float*)d_out : xw);
  }
}

// Round 14
// 2514.928 us; speedup vs baseline: 1.0502x; 1.0502x over previous
//
#include <hip/hip_runtime.h>

typedef __bf16 bf16x8 __attribute__((ext_vector_type(8)));
typedef float f32x4 __attribute__((ext_vector_type(4)));
typedef unsigned short ushort8_t __attribute__((ext_vector_type(8)));
typedef unsigned short ushort4_t __attribute__((ext_vector_type(4)));

#define MFMA16(a, b, c) __builtin_amdgcn_mfma_f32_16x16x32_bf16((a), (b), (c), 0, 0, 0)

#define GLOAD16(gp, lp)                                                        \
  __builtin_amdgcn_global_load_lds(                                            \
      (__attribute__((address_space(1))) void*)(gp),                           \
      (__attribute__((address_space(3))) void*)(lp), 16, 0, 0)

__device__ __forceinline__ unsigned short f2bf(float f) {
  unsigned u = __builtin_bit_cast(unsigned, f);
  return (unsigned short)((u + 0x7FFFu + ((u >> 16) & 1u)) >> 16);
}

// Tiled ("staging-order") layout for GEMM operands, [R][K] logical:
//   addr(r,k) = ((r>>4)*(K>>5) + (k>>5))*512 + ((k>>3)&3)*128 + (r&15)*8 + (k&7)
// One 16x32 tile = 512 contiguous elems = one GLOAD16; LDS linear; fragment
// ds_read_b128 at base + l*16B: conflict-free; staging fully coalesced.

// ---------------------------------------------------------------------------
__global__ __launch_bounds__(256) void transpose_f2b_tiled(
    const float* __restrict__ src, unsigned short* __restrict__ dst,
    int Kdim, int Ndim) {
  const long u = (long)blockIdx.x * 256 + threadIdx.x;  // 16B unit
  const long total = ((long)Kdim * Ndim) >> 3;
  if (u >= total) return;
  const int kt32 = Kdim >> 5;
  const long tile = u >> 6;
  const int t8 = (int)(u & 63);
  const int chunk = t8 >> 4, rowlow = t8 & 15;
  const int n = (int)(tile / kt32) * 16 + rowlow;
  const int k0 = (int)(tile % kt32) * 32 + chunk * 8;
  ushort8_t o;
#pragma unroll
  for (int e = 0; e < 8; e++) o[e] = f2bf(src[(long)(k0 + e) * Ndim + n]);
  *(ushort8_t*)(dst + (u << 3)) = o;
}

// ---------------------------------------------------------------------------
__global__ __launch_bounds__(256) void ln_kernel(
    const float* __restrict__ x, const float* __restrict__ gw,
    const float* __restrict__ gb, unsigned short* __restrict__ h) {
  const int row = blockIdx.x * 4 + (threadIdx.x >> 6);
  const int l = threadIdx.x & 63;
  const float* xr = x + (long)row * 768;
  f32x4 va[3];
#pragma unroll
  for (int i = 0; i < 3; i++) va[i] = *(const f32x4*)(xr + i * 256 + l * 4);
  float s = 0.f, ss = 0.f;
#pragma unroll
  for (int i = 0; i < 3; i++)
#pragma unroll
    for (int j = 0; j < 4; j++) {
      float t = va[i][j];
      s += t;
      ss += t * t;
    }
#pragma unroll
  for (int off = 1; off < 64; off <<= 1) {
    s += __shfl_xor(s, off, 64);
    ss += __shfl_xor(ss, off, 64);
  }
  const float mu = s * (1.f / 768.f);
  const float var = ss * (1.f / 768.f) - mu * mu;
  const float inv = rsqrtf(var + 1e-5f);
  const long tb = ((long)(row >> 4) * 24) << 9;
  const int rlow = (row & 15) * 8;
  const int coff = ((l >> 1) & 3) * 128 + rlow + (l & 1) * 4;
#pragma unroll
  for (int i = 0; i < 3; i++) {
    f32x4 wv = *(const f32x4*)(gw + i * 256 + l * 4);
    f32x4 bv = *(const f32x4*)(gb + i * 256 + l * 4);
    ushort4_t o;
#pragma unroll
    for (int j = 0; j < 4; j++) o[j] = f2bf((va[i][j] - mu) * inv * wv[j] + bv[j]);
    const long addr = tb + ((long)(i * 8 + (l >> 3)) << 9) + coff;
    *(ushort4_t*)(h + addr) = o;
  }
}

enum { EPI_QKV = 0, EPI_GELU = 1, EPI_RES = 2 };

// ---------------------------------------------------------------------------
// GEMM on TILED operands (R9/R12-proven loop): tile BM x 128 (BM = MREP*32),
// 4 waves, BK=64 two-plane, 2-phase dbuf, one __syncthreads per K-step.
// SX>0: supertile block ordering -- the 8 XCD-contiguous wg ranges (via the
// bijective swizzle) each decode to one SX*SY set (bx-fast inner), so each
// XCD's L2 working set is A-panel(SY*BM rows) + B-panel(SX*128 cols) <= 4MB.
template <int EPI, int MREP, int SX, int SY>
__global__ __launch_bounds__(256) void gemm_bt(
    const unsigned short* __restrict__ A, const unsigned short* __restrict__ BT,
    int K, const float* __restrict__ bb0, const float* __restrict__ bb1,
    const float* __restrict__ bb2, unsigned short* __restrict__ o0,
    unsigned short* __restrict__ o1, unsigned short* __restrict__ o2,
    const float* oFin, float* oFout) {
  constexpr int BM = MREP * 32;
  constexpr int AG = BM / 16;  // A row-groups
  __shared__ unsigned short As[2][2][AG * 512];
  __shared__ unsigned short Bs[2][2][8 * 512];
  const int tid = threadIdx.x;
  const int w = tid >> 6, l = tid & 63;
  const int lr = l & 15, lg = l >> 4;
  const int wr = w >> 1, wc = w & 1;

  const int nx = gridDim.x;
  const int nwg = nx * gridDim.y;
  int wg = blockIdx.y * nx + blockIdx.x;
  {
    const int qq = nwg >> 3, rr = nwg & 7;
    const int xcd = wg & 7, idx = wg >> 3;
    wg = (xcd < rr ? xcd * (qq + 1) : rr * (qq + 1) + (xcd - rr) * qq) + idx;
  }
  int bx, by;
  if (SX > 0) {
    const int setsz = SX * SY;
    const int s = wg / setsz, r2 = wg - s * setsz;
    const int nsx = nx / SX;
    bx = (s % nsx) * SX + r2 % SX;
    by = (s / nsx) * SY + r2 / SX;
  } else {
    bx = wg % nx;
    by = wg / nx;
  }
  const int m0 = by * BM, n0 = bx * 128;

  const int nk32 = K >> 5;
  const long abase = (long)(m0 >> 4) * nk32;
  const long bbase = (long)(n0 >> 4) * nk32;

  auto stage = [&](int buf, int kt) {
#pragma unroll
    for (int kk = 0; kk < 2; kk++) {
      const int pk = kt * 2 + kk;
#pragma unroll
      for (int t = 0; t < AG / 4; t++) {
        const int g = w + t * 4;
        GLOAD16(A + ((abase + (long)g * nk32 + pk) << 9) + l * 8,
                &As[buf][kk][g * 512 + l * 8]);
      }
#pragma unroll
      for (int t = 0; t < 2; t++) {
        const int g = w + t * 4;
        GLOAD16(BT + ((bbase + (long)g * nk32 + pk) << 9) + l * 8,
                &Bs[buf][kk][g * 512 + l * 8]);
      }
    }
  };

  f32x4 acc[MREP][4] = {};
  const int nk = K >> 6;
  stage(0, 0);
  for (int kt = 0; kt < nk; ++kt) {
    const int cur = kt & 1;
    __syncthreads();  // drains stage(kt), issued one full compute-step ago
    if (kt + 1 < nk) stage(cur ^ 1, kt + 1);
#pragma unroll
    for (int kk = 0; kk < 2; kk++) {
      bf16x8 a[MREP], b[4];
#pragma unroll
      for (int i = 0; i < MREP; i++)
        a[i] = *(const bf16x8*)(&As[cur][kk][(wr * MREP + i) * 512 + l * 8]);
#pragma unroll
      for (int j = 0; j < 4; j++)
        b[j] = *(const bf16x8*)(&Bs[cur][kk][(wc * 4 + j) * 512 + l * 8]);
      __builtin_amdgcn_s_setprio(1);
#pragma unroll
      for (int i = 0; i < MREP; i++)
#pragma unroll
        for (int j = 0; j < 4; j++) acc[i][j] = MFMA16(a[i], b[j], acc[i][j]);
      __builtin_amdgcn_s_setprio(0);
    }
  }

  // ----- epilogue -----
  if (EPI == EPI_QKV) {
    const int whichq = n0 / 768;
    const int cc0 = n0 - whichq * 768;
    const float* bias = whichq == 0 ? bb0 : whichq == 1 ? bb1 : bb2;
    if (whichq < 2) {
      unsigned short* dst = whichq == 0 ? o0 : o1;
#pragma unroll
      for (int i = 0; i < MREP; i++) {
        const int r = m0 + wr * MREP * 16 + i * 16 + lg * 4;
#pragma unroll
        for (int j = 0; j < 4; j++) {
          const int ccol = cc0 + wc * 64 + j * 16 + lr;
          const int hd = ccol >> 6, d = ccol & 63;
          const float bv = bias[ccol];
#pragma unroll
          for (int q = 0; q < 4; q++) {
            const int row = r + q;
            const int bidx = row >> 9, n = row & 511;
            const long addr = ((long)(bidx * 12 + hd) * 512 + n) * 64 + d;
            dst[addr] = f2bf(acc[i][j][q] + bv);
          }
        }
      }
    } else {
#pragma unroll
      for (int i = 0; i < MREP; i++) {
        const int r = m0 + wr * MREP * 16 + i * 16 + lg * 4;
        const int bidx = r >> 9, nb = r & 511;
#pragma unroll
        for (int j = 0; j < 4; j++) {
          const int ccol = cc0 + wc * 64 + j * 16 + lr;
          const int hd = ccol >> 6, d = ccol & 63;
          const float bv = bias[ccol];
          ushort4_t pk;
#pragma unroll
          for (int q = 0; q < 4; q++) pk[q] = f2bf(acc[i][j][q] + bv);
          *(ushort4_t*)(&o2[((long)(bidx * 12 + hd) * 64 + d) * 512 + nb]) = pk;
        }
      }
    }
  } else if (EPI == EPI_GELU) {
#pragma unroll
    for (int i = 0; i < MREP; i++) {
      const int r = m0 + wr * MREP * 16 + i * 16 + lg * 4;
#pragma unroll
      for (int j = 0; j < 4; j++) {
        const int c = n0 + wc * 64 + j * 16 + lr;
        const float bv = bb0[c];
        const long cpart = ((long)(c >> 5) << 9) + ((c >> 3) & 3) * 128 + (c & 7);
#pragma unroll
        for (int q = 0; q < 4; q++) {
          const int row = r + q;
          float v = acc[i][j][q] + bv;
          const float u = v * (0.7978845608f + 0.0356774081f * v * v);
          const float g = v / (1.0f + __expf(-2.0f * u));
          o0[(((long)(row >> 4) * 96) << 9) + cpart + (row & 15) * 8] = f2bf(g);
        }
      }
    }
  } else {
#pragma unroll
    for (int i = 0; i < MREP; i++) {
      const int r = m0 + wr * MREP * 16 + i * 16 + lg * 4;
#pragma unroll
      for (int j = 0; j < 4; j++) {
        const int c = n0 + wc * 64 + j * 16 + lr;
        const float bv = bb0[c];
#pragma unroll
        for (int q = 0; q < 4; q++) {
          const long addr = (long)(r + q) * 768 + c;
          oFout[addr] = acc[i][j][q] + bv + oFin[addr];
        }
      }
    }
  }
}

// ---------------------------------------------------------------------------
// Flash attention (R7-proven, unchanged).
__global__ __launch_bounds__(256) void attn_kernel(
    const unsigned short* __restrict__ qg, const unsigned short* __restrict__ kg,
    const unsigned short* __restrict__ vtg, float* __restrict__ x) {
  __shared__ unsigned short Sh[128 * 64];
  __shared__ unsigned short Ks[2][64 * 64];
  __shared__ unsigned short Vt[2][64 * 64];
  const int qt = blockIdx.x, h = blockIdx.y, b = blockIdx.z;
  const int bh = b * 12 + h;
  const int tid = threadIdx.x, w = tid >> 6, l = tid & 63;
  const int lr = l & 15, lg = l >> 4;
  const int fchunk = ((l & 7) ^ ((l >> 3) & 7)) * 8;
  const int rk = lr & 7;

  const unsigned short* qbase =
      qg + ((long)bh * 512 + qt * 128 + w * 32 + (l >> 3)) * 64 + fchunk;
  unsigned short* shW = &Sh[w * 2048 + l * 8];
#pragma unroll
  for (int cc = 0; cc < 4; cc++) GLOAD16(qbase + cc * 8 * 64, shW + cc * 512);

  const unsigned short* kbase =
      kg + ((long)bh * 512 + w * 16 + (l >> 3)) * 64 + fchunk;
  const unsigned short* vbase =
      vtg + ((long)bh * 64 + w * 16 + (l >> 3)) * 512 + fchunk;
  unsigned short* KsW = &Ks[0][w * 1024 + l * 8];
  unsigned short* VtW = &Vt[0][w * 1024 + l * 8];

  auto stageKV = [&](int buf, int kt) {
#pragma unroll
    for (int cc = 0; cc < 2; cc++) {
      GLOAD16(kbase + (kt * 64 + cc * 8) * 64, KsW + buf * 4096 + cc * 512);
      GLOAD16(vbase + cc * 8 * 512 + kt * 64, VtW + buf * 4096 + cc * 512);
    }
  };
  stageKV(0, 0);
  __syncthreads();

  bf16x8 qa[2][2];
#pragma unroll
  for (int mi = 0; mi < 2; mi++)
#pragma unroll
    for (int ds = 0; ds < 2; ds++) {
      qa[mi][ds] = *(const bf16x8*)(&Sh[(w * 32 + mi * 16 + lr) * 64 +
                                        ((ds * 4 + lg) ^ rk) * 8]);
#pragma unroll
      for (int e = 0; e < 8; e++)
        qa[mi][ds][e] = (__bf16)(0.125f * (float)qa[mi][ds][e]);
    }

  unsigned short* Pw = &Sh[w * 2048];
  float lsum[8] = {};
  f32x4 o[2][4] = {};

  for (int kt = 0; kt < 8; ++kt) {
    const int cur = kt & 1;
    if (kt < 7) stageKV(cur ^ 1, kt + 1);

    f32x4 s[2][4] = {};
#pragma unroll
    for (int ds = 0; ds < 2; ++ds) {
      bf16x8 kb[4];
#pragma unroll
      for (int nj = 0; nj < 4; nj++)
        kb[nj] = *(const bf16x8*)(&Ks[cur][(nj * 16 + lr) * 64 +
                                           ((ds * 4 + lg) ^ rk) * 8]);
#pragma unroll
      for (int mi = 0; mi < 2; mi++)
#pragma unroll
        for (int nj = 0; nj < 4; nj++) s[mi][nj] = MFMA16(qa[mi][ds], kb[nj], s[mi][nj]);
    }

#pragma unroll
    for (int mi = 0; mi < 2; mi++)
#pragma unroll
      for (int nj = 0; nj < 4; nj++) {
        const int cL = nj * 2 + (lr >> 3);
#pragma unroll
        for (int q = 0; q < 4; q++) {
          const int row = mi * 16 + lg * 4 + q;
          const float p = __expf(s[mi][nj][q]);
          lsum[mi * 4 + q] += p;
          Pw[row * 64 + ((cL ^ (row & 7)) * 8) + (lr & 7)] = f2bf(p);
        }
      }

#pragma unroll
    for (int ks = 0; ks < 2; ++ks) {
      bf16x8 pa[2], vb[4];
#pragma unroll
      for (int mi = 0; mi < 2; mi++)
        pa[mi] = *(const bf16x8*)(&Pw[(mi * 16 + lr) * 64 +
                                      ((ks * 4 + lg) ^ rk) * 8]);
#pragma unroll
      for (int dj = 0; dj < 4; dj++)
        vb[dj] = *(const bf16x8*)(&Vt[cur][(dj * 16 + lr) * 64 +
                                           ((ks * 4 + lg) ^ rk) * 8]);
#pragma unroll
      for (int mi = 0; mi < 2; mi++)
#pragma unroll
        for (int dj = 0; dj < 4; dj++) o[mi][dj] = MFMA16(pa[mi], vb[dj], o[mi][dj]);
    }
    __syncthreads();
  }

#pragma unroll
  for (int i = 0; i < 8; i++) {
#pragma unroll
    for (int off = 1; off < 16; off <<= 1) lsum[i] += __shfl_xor(lsum[i], off, 64);
  }

#pragma unroll
  for (int mi = 0; mi < 2; mi++) {
#pragma unroll
    for (int q = 0; q < 4; q++) {
      const int n = qt * 128 + w * 32 + mi * 16 + lg * 4 + q;
      const float inv = 1.0f / lsum[mi * 4 + q];
      const long base = ((long)(b * 512 + n)) * 768 + h * 64;
#pragma unroll
      for (int dj = 0; dj < 4; dj++) {
        const long a = base + dj * 16 + lr;
        x[a] = x[a] + o[mi][dj][q] * inv;
      }
    }
  }
}

// ---------------------------------------------------------------------------
extern "C" void kernel_launch(void* const* d_in, const int* in_sizes, int n_in,
                              void* d_out, int out_size, void* d_ws,
                              size_t ws_size, hipStream_t stream) {
  const float* x_in = (const float*)d_in[0];
  const float* ln_w = (const float*)d_in[1];
  const float* ln_b = (const float*)d_in[2];
  const float* wq = (const float*)d_in[3];
  const float* bq = (const float*)d_in[4];
  const float* wk = (const float*)d_in[5];
  const float* bk = (const float*)d_in[6];
  const float* wv = (const float*)d_in[7];
  const float* bv = (const float*)d_in[8];
  const float* w1 = (const float*)d_in[9];
  const float* b1 = (const float*)d_in[10];
  const float* w2 = (const float*)d_in[11];
  const float* b2 = (const float*)d_in[12];

  char* p = (char*)d_ws;
  float* xw = (float*)p;            p += 8192L * 768 * 4;
  unsigned short* hbuf = (unsigned short*)p;  p += 8192L * 768 * 2;
  unsigned short* wqkvT = (unsigned short*)p; p += 2304L * 768 * 2;
  unsigned short* w1T = (unsigned short*)p;   p += 3072L * 768 * 2;
  unsigned short* w2T = (unsigned short*)p;   p += 768L * 3072 * 2;
  unsigned short* qb = (unsigned short*)p;
  unsigned short* kb = qb + 6291456L;
  unsigned short* vt = kb + 6291456L;
  unsigned short* gbuf = qb;  // MLP hidden reuses q/k/v region

  hipMemcpyAsync(xw, x_in, 8192L * 768 * 4, hipMemcpyDeviceToDevice, stream);

  transpose_f2b_tiled<<<(768 * 768 / 8 + 255) / 256, 256, 0, stream>>>(
      wq, wqkvT, 768, 768);
  transpose_f2b_tiled<<<(768 * 768 / 8 + 255) / 256, 256, 0, stream>>>(
      wk, wqkvT + 768L * 768, 768, 768);
  transpose_f2b_tiled<<<(768 * 768 / 8 + 255) / 256, 256, 0, stream>>>(
      wv, wqkvT + 2L * 768 * 768, 768, 768);
  transpose_f2b_tiled<<<(768 * 3072 / 8 + 255) / 256, 256, 0, stream>>>(
      w1, w1T, 768, 3072);
  transpose_f2b_tiled<<<(768 * 3072 / 8 + 255) / 256, 256, 0, stream>>>(
      w2, w2T, 3072, 768);

  for (int layer = 0; layer < 12; ++layer) {
    ln_kernel<<<2048, 256, 0, stream>>>(xw, ln_w, ln_b, hbuf);
    // supertile sets 9bx x 16by (footprint ~5 MB/XCD)
    gemm_bt<EPI_QKV, 4, 9, 16><<<dim3(18, 64), 256, 0, stream>>>(
        hbuf, wqkvT, 768, bq, bk, bv, qb, kb, vt, nullptr, nullptr);
    attn_kernel<<<dim3(4, 12, 16), 256, 0, stream>>>(qb, kb, vt, xw);
    ln_kernel<<<2048, 256, 0, stream>>>(xw, ln_w, ln_b, hbuf);
    // supertile sets 12bx x 32by (footprint ~5.6 MB/XCD)
    gemm_bt<EPI_GELU, 2, 12, 32><<<dim3(24, 128), 256, 0, stream>>>(
        hbuf, w1T, 768, b1, nullptr, nullptr, gbuf, nullptr, nullptr, nullptr,
        nullptr);
    gemm_bt<EPI_RES, 2, 0, 0><<<dim3(6, 128), 256, 0, stream>>>(
        gbuf, w2T, 3072, b2, nullptr, nullptr, nullptr, nullptr, nullptr, xw,
        layer == 11 ? (float*)d_out : xw);
  }
}

// Round 15
// 2473.890 us; speedup vs baseline: 1.0676x; 1.0166x over previous
//
#include <hip/hip_runtime.h>

typedef __bf16 bf16x8 __attribute__((ext_vector_type(8)));
typedef float f32x4 __attribute__((ext_vector_type(4)));
typedef unsigned short ushort8_t __attribute__((ext_vector_type(8)));
typedef unsigned short ushort4_t __attribute__((ext_vector_type(4)));

#define MFMA16(a, b, c) __builtin_amdgcn_mfma_f32_16x16x32_bf16((a), (b), (c), 0, 0, 0)

#define GLOAD16(gp, lp)                                                        \
  __builtin_amdgcn_global_load_lds(                                            \
      (__attribute__((address_space(1))) void*)(gp),                           \
      (__attribute__((address_space(3))) void*)(lp), 16, 0, 0)

__device__ __forceinline__ unsigned short f2bf(float f) {
  unsigned u = __builtin_bit_cast(unsigned, f);
  return (unsigned short)((u + 0x7FFFu + ((u >> 16) & 1u)) >> 16);
}

// Tiled ("staging-order") layout for GEMM operands, [R][K] logical:
//   addr(r,k) = ((r>>4)*(K>>5) + (k>>5))*512 + ((k>>3)&3)*128 + (r&15)*8 + (k&7)
// One 16x32 tile = 512 contiguous elems = one GLOAD16; LDS linear; fragment
// ds_read_b128 at base + l*16B: conflict-free; staging fully coalesced.

// ---------------------------------------------------------------------------
__global__ __launch_bounds__(256) void transpose_f2b_tiled(
    const float* __restrict__ src, unsigned short* __restrict__ dst,
    int Kdim, int Ndim) {
  const long u = (long)blockIdx.x * 256 + threadIdx.x;  // 16B unit
  const long total = ((long)Kdim * Ndim) >> 3;
  if (u >= total) return;
  const int kt32 = Kdim >> 5;
  const long tile = u >> 6;
  const int t8 = (int)(u & 63);
  const int chunk = t8 >> 4, rowlow = t8 & 15;
  const int n = (int)(tile / kt32) * 16 + rowlow;
  const int k0 = (int)(tile % kt32) * 32 + chunk * 8;
  ushort8_t o;
#pragma unroll
  for (int e = 0; e < 8; e++) o[e] = f2bf(src[(long)(k0 + e) * Ndim + n]);
  *(ushort8_t*)(dst + (u << 3)) = o;
}

// ---------------------------------------------------------------------------
__global__ __launch_bounds__(256) void ln_kernel(
    const float* __restrict__ x, const float* __restrict__ gw,
    const float* __restrict__ gb, unsigned short* __restrict__ h) {
  const int row = blockIdx.x * 4 + (threadIdx.x >> 6);
  const int l = threadIdx.x & 63;
  const float* xr = x + (long)row * 768;
  f32x4 va[3];
#pragma unroll
  for (int i = 0; i < 3; i++) va[i] = *(const f32x4*)(xr + i * 256 + l * 4);
  float s = 0.f, ss = 0.f;
#pragma unroll
  for (int i = 0; i < 3; i++)
#pragma unroll
    for (int j = 0; j < 4; j++) {
      float t = va[i][j];
      s += t;
      ss += t * t;
    }
#pragma unroll
  for (int off = 1; off < 64; off <<= 1) {
    s += __shfl_xor(s, off, 64);
    ss += __shfl_xor(ss, off, 64);
  }
  const float mu = s * (1.f / 768.f);
  const float var = ss * (1.f / 768.f) - mu * mu;
  const float inv = rsqrtf(var + 1e-5f);
  const long tb = ((long)(row >> 4) * 24) << 9;
  const int rlow = (row & 15) * 8;
  const int coff = ((l >> 1) & 3) * 128 + rlow + (l & 1) * 4;
#pragma unroll
  for (int i = 0; i < 3; i++) {
    f32x4 wv = *(const f32x4*)(gw + i * 256 + l * 4);
    f32x4 bv = *(const f32x4*)(gb + i * 256 + l * 4);
    ushort4_t o;
#pragma unroll
    for (int j = 0; j < 4; j++) o[j] = f2bf((va[i][j] - mu) * inv * wv[j] + bv[j]);
    const long addr = tb + ((long)(i * 8 + (l >> 3)) << 9) + coff;
    *(ushort4_t*)(h + addr) = o;
  }
}

enum { EPI_QKV = 0, EPI_GELU = 1, EPI_RES = 2 };

// ---------------------------------------------------------------------------
// GEMM on TILED operands (R9/R12-proven loop): tile BM x 128 (BM = MREP*32),
// 4 waves, BK=64 two-plane, 2-phase dbuf, one __syncthreads per K-step.
// SX>0: supertile block ordering -- the 8 XCD-contiguous wg ranges (via the
// bijective swizzle) each decode to one SX*SY set (bx-fast inner), so each
// XCD's L2 working set is B-panel(SX*128 cols, resident) + streaming A.
template <int EPI, int MREP, int SX, int SY>
__global__ __launch_bounds__(256) void gemm_bt(
    const unsigned short* __restrict__ A, const unsigned short* __restrict__ BT,
    int K, const float* __restrict__ bb0, const float* __restrict__ bb1,
    const float* __restrict__ bb2, unsigned short* __restrict__ o0,
    unsigned short* __restrict__ o1, unsigned short* __restrict__ o2,
    const float* oFin, float* oFout) {
  constexpr int BM = MREP * 32;
  constexpr int AG = BM / 16;  // A row-groups
  __shared__ unsigned short As[2][2][AG * 512];
  __shared__ unsigned short Bs[2][2][8 * 512];
  const int tid = threadIdx.x;
  const int w = tid >> 6, l = tid & 63;
  const int lr = l & 15, lg = l >> 4;
  const int wr = w >> 1, wc = w & 1;

  const int nx = gridDim.x;
  const int nwg = nx * gridDim.y;
  int wg = blockIdx.y * nx + blockIdx.x;
  {
    const int qq = nwg >> 3, rr = nwg & 7;
    const int xcd = wg & 7, idx = wg >> 3;
    wg = (xcd < rr ? xcd * (qq + 1) : rr * (qq + 1) + (xcd - rr) * qq) + idx;
  }
  int bx, by;
  if (SX > 0) {
    const int setsz = SX * SY;
    const int s = wg / setsz, r2 = wg - s * setsz;
    const int nsx = nx / SX;
    bx = (s % nsx) * SX + r2 % SX;
    by = (s / nsx) * SY + r2 / SX;
  } else {
    bx = wg % nx;
    by = wg / nx;
  }
  const int m0 = by * BM, n0 = bx * 128;

  const int nk32 = K >> 5;
  const long abase = (long)(m0 >> 4) * nk32;
  const long bbase = (long)(n0 >> 4) * nk32;

  auto stage = [&](int buf, int kt) {
#pragma unroll
    for (int kk = 0; kk < 2; kk++) {
      const int pk = kt * 2 + kk;
#pragma unroll
      for (int t = 0; t < AG / 4; t++) {
        const int g = w + t * 4;
        GLOAD16(A + ((abase + (long)g * nk32 + pk) << 9) + l * 8,
                &As[buf][kk][g * 512 + l * 8]);
      }
#pragma unroll
      for (int t = 0; t < 2; t++) {
        const int g = w + t * 4;
        GLOAD16(BT + ((bbase + (long)g * nk32 + pk) << 9) + l * 8,
                &Bs[buf][kk][g * 512 + l * 8]);
      }
    }
  };

  f32x4 acc[MREP][4] = {};
  const int nk = K >> 6;
  stage(0, 0);
  for (int kt = 0; kt < nk; ++kt) {
    const int cur = kt & 1;
    __syncthreads();  // drains stage(kt), issued one full compute-step ago
    if (kt + 1 < nk) stage(cur ^ 1, kt + 1);
#pragma unroll
    for (int kk = 0; kk < 2; kk++) {
      bf16x8 a[MREP], b[4];
#pragma unroll
      for (int i = 0; i < MREP; i++)
        a[i] = *(const bf16x8*)(&As[cur][kk][(wr * MREP + i) * 512 + l * 8]);
#pragma unroll
      for (int j = 0; j < 4; j++)
        b[j] = *(const bf16x8*)(&Bs[cur][kk][(wc * 4 + j) * 512 + l * 8]);
      __builtin_amdgcn_s_setprio(1);
#pragma unroll
      for (int i = 0; i < MREP; i++)
#pragma unroll
        for (int j = 0; j < 4; j++) acc[i][j] = MFMA16(a[i], b[j], acc[i][j]);
      __builtin_amdgcn_s_setprio(0);
    }
  }

  // ----- epilogue -----
  if (EPI == EPI_QKV) {
    const int whichq = n0 / 768;
    const int cc0 = n0 - whichq * 768;
    const float* bias = whichq == 0 ? bb0 : whichq == 1 ? bb1 : bb2;
    if (whichq < 2) {
      unsigned short* dst = whichq == 0 ? o0 : o1;
#pragma unroll
      for (int i = 0; i < MREP; i++) {
        const int r = m0 + wr * MREP * 16 + i * 16 + lg * 4;
#pragma unroll
        for (int j = 0; j < 4; j++) {
          const int ccol = cc0 + wc * 64 + j * 16 + lr;
          const int hd = ccol >> 6, d = ccol & 63;
          const float bv = bias[ccol];
#pragma unroll
          for (int q = 0; q < 4; q++) {
            const int row = r + q;
            const int bidx = row >> 9, n = row & 511;
            const long addr = ((long)(bidx * 12 + hd) * 512 + n) * 64 + d;
            dst[addr] = f2bf(acc[i][j][q] + bv);
          }
        }
      }
    } else {
#pragma unroll
      for (int i = 0; i < MREP; i++) {
        const int r = m0 + wr * MREP * 16 + i * 16 + lg * 4;
        const int bidx = r >> 9, nb = r & 511;
#pragma unroll
        for (int j = 0; j < 4; j++) {
          const int ccol = cc0 + wc * 64 + j * 16 + lr;
          const int hd = ccol >> 6, d = ccol & 63;
          const float bv = bias[ccol];
          ushort4_t pk;
#pragma unroll
          for (int q = 0; q < 4; q++) pk[q] = f2bf(acc[i][j][q] + bv);
          *(ushort4_t*)(&o2[((long)(bidx * 12 + hd) * 64 + d) * 512 + nb]) = pk;
        }
      }
    }
  } else if (EPI == EPI_GELU) {
#pragma unroll
    for (int i = 0; i < MREP; i++) {
      const int r = m0 + wr * MREP * 16 + i * 16 + lg * 4;
#pragma unroll
      for (int j = 0; j < 4; j++) {
        const int c = n0 + wc * 64 + j * 16 + lr;
        const float bv = bb0[c];
        const long cpart = ((long)(c >> 5) << 9) + ((c >> 3) & 3) * 128 + (c & 7);
#pragma unroll
        for (int q = 0; q < 4; q++) {
          const int row = r + q;
          float v = acc[i][j][q] + bv;
          const float u = v * (0.7978845608f + 0.0356774081f * v * v);
          const float g = v / (1.0f + __expf(-2.0f * u));
          o0[(((long)(row >> 4) * 96) << 9) + cpart + (row & 15) * 8] = f2bf(g);
        }
      }
    }
  } else {
#pragma unroll
    for (int i = 0; i < MREP; i++) {
      const int r = m0 + wr * MREP * 16 + i * 16 + lg * 4;
#pragma unroll
      for (int j = 0; j < 4; j++) {
        const int c = n0 + wc * 64 + j * 16 + lr;
        const float bv = bb0[c];
#pragma unroll
        for (int q = 0; q < 4; q++) {
          const long addr = (long)(r + q) * 768 + c;
          oFout[addr] = acc[i][j][q] + bv + oFin[addr];
        }
      }
    }
  }
}

// ---------------------------------------------------------------------------
// Flash attention (R7-proven, unchanged).
__global__ __launch_bounds__(256) void attn_kernel(
    const unsigned short* __restrict__ qg, const unsigned short* __restrict__ kg,
    const unsigned short* __restrict__ vtg, float* __restrict__ x) {
  __shared__ unsigned short Sh[128 * 64];
  __shared__ unsigned short Ks[2][64 * 64];
  __shared__ unsigned short Vt[2][64 * 64];
  const int qt = blockIdx.x, h = blockIdx.y, b = blockIdx.z;
  const int bh = b * 12 + h;
  const int tid = threadIdx.x, w = tid >> 6, l = tid & 63;
  const int lr = l & 15, lg = l >> 4;
  const int fchunk = ((l & 7) ^ ((l >> 3) & 7)) * 8;
  const int rk = lr & 7;

  const unsigned short* qbase =
      qg + ((long)bh * 512 + qt * 128 + w * 32 + (l >> 3)) * 64 + fchunk;
  unsigned short* shW = &Sh[w * 2048 + l * 8];
#pragma unroll
  for (int cc = 0; cc < 4; cc++) GLOAD16(qbase + cc * 8 * 64, shW + cc * 512);

  const unsigned short* kbase =
      kg + ((long)bh * 512 + w * 16 + (l >> 3)) * 64 + fchunk;
  const unsigned short* vbase =
      vtg + ((long)bh * 64 + w * 16 + (l >> 3)) * 512 + fchunk;
  unsigned short* KsW = &Ks[0][w * 1024 + l * 8];
  unsigned short* VtW = &Vt[0][w * 1024 + l * 8];

  auto stageKV = [&](int buf, int kt) {
#pragma unroll
    for (int cc = 0; cc < 2; cc++) {
      GLOAD16(kbase + (kt * 64 + cc * 8) * 64, KsW + buf * 4096 + cc * 512);
      GLOAD16(vbase + cc * 8 * 512 + kt * 64, VtW + buf * 4096 + cc * 512);
    }
  };
  stageKV(0, 0);
  __syncthreads();

  bf16x8 qa[2][2];
#pragma unroll
  for (int mi = 0; mi < 2; mi++)
#pragma unroll
    for (int ds = 0; ds < 2; ds++) {
      qa[mi][ds] = *(const bf16x8*)(&Sh[(w * 32 + mi * 16 + lr) * 64 +
                                        ((ds * 4 + lg) ^ rk) * 8]);
#pragma unroll
      for (int e = 0; e < 8; e++)
        qa[mi][ds][e] = (__bf16)(0.125f * (float)qa[mi][ds][e]);
    }

  unsigned short* Pw = &Sh[w * 2048];
  float lsum[8] = {};
  f32x4 o[2][4] = {};

  for (int kt = 0; kt < 8; ++kt) {
    const int cur = kt & 1;
    if (kt < 7) stageKV(cur ^ 1, kt + 1);

    f32x4 s[2][4] = {};
#pragma unroll
    for (int ds = 0; ds < 2; ++ds) {
      bf16x8 kb[4];
#pragma unroll
      for (int nj = 0; nj < 4; nj++)
        kb[nj] = *(const bf16x8*)(&Ks[cur][(nj * 16 + lr) * 64 +
                                           ((ds * 4 + lg) ^ rk) * 8]);
#pragma unroll
      for (int mi = 0; mi < 2; mi++)
#pragma unroll
        for (int nj = 0; nj < 4; nj++) s[mi][nj] = MFMA16(qa[mi][ds], kb[nj], s[mi][nj]);
    }

#pragma unroll
    for (int mi = 0; mi < 2; mi++)
#pragma unroll
      for (int nj = 0; nj < 4; nj++) {
        const int cL = nj * 2 + (lr >> 3);
#pragma unroll
        for (int q = 0; q < 4; q++) {
          const int row = mi * 16 + lg * 4 + q;
          const float p = __expf(s[mi][nj][q]);
          lsum[mi * 4 + q] += p;
          Pw[row * 64 + ((cL ^ (row & 7)) * 8) + (lr & 7)] = f2bf(p);
        }
      }

#pragma unroll
    for (int ks = 0; ks < 2; ++ks) {
      bf16x8 pa[2], vb[4];
#pragma unroll
      for (int mi = 0; mi < 2; mi++)
        pa[mi] = *(const bf16x8*)(&Pw[(mi * 16 + lr) * 64 +
                                      ((ks * 4 + lg) ^ rk) * 8]);
#pragma unroll
      for (int dj = 0; dj < 4; dj++)
        vb[dj] = *(const bf16x8*)(&Vt[cur][(dj * 16 + lr) * 64 +
                                           ((ks * 4 + lg) ^ rk) * 8]);
#pragma unroll
      for (int mi = 0; mi < 2; mi++)
#pragma unroll
        for (int dj = 0; dj < 4; dj++) o[mi][dj] = MFMA16(pa[mi], vb[dj], o[mi][dj]);
    }
    __syncthreads();
  }

#pragma unroll
  for (int i = 0; i < 8; i++) {
#pragma unroll
    for (int off = 1; off < 16; off <<= 1) lsum[i] += __shfl_xor(lsum[i], off, 64);
  }

#pragma unroll
  for (int mi = 0; mi < 2; mi++) {
#pragma unroll
    for (int q = 0; q < 4; q++) {
      const int n = qt * 128 + w * 32 + mi * 16 + lg * 4 + q;
      const float inv = 1.0f / lsum[mi * 4 + q];
      const long base = ((long)(b * 512 + n)) * 768 + h * 64;
#pragma unroll
      for (int dj = 0; dj < 4; dj++) {
        const long a = base + dj * 16 + lr;
        x[a] = x[a] + o[mi][dj][q] * inv;
      }
    }
  }
}

// ---------------------------------------------------------------------------
extern "C" void kernel_launch(void* const* d_in, const int* in_sizes, int n_in,
                              void* d_out, int out_size, void* d_ws,
                              size_t ws_size, hipStream_t stream) {
  const float* x_in = (const float*)d_in[0];
  const float* ln_w = (const float*)d_in[1];
  const float* ln_b = (const float*)d_in[2];
  const float* wq = (const float*)d_in[3];
  const float* bq = (const float*)d_in[4];
  const float* wk = (const float*)d_in[5];
  const float* bk = (const float*)d_in[6];
  const float* wv = (const float*)d_in[7];
  const float* bv = (const float*)d_in[8];
  const float* w1 = (const float*)d_in[9];
  const float* b1 = (const float*)d_in[10];
  const float* w2 = (const float*)d_in[11];
  const float* b2 = (const float*)d_in[12];

  char* p = (char*)d_ws;
  float* xw = (float*)p;            p += 8192L * 768 * 4;
  unsigned short* hbuf = (unsigned short*)p;  p += 8192L * 768 * 2;
  unsigned short* wqkvT = (unsigned short*)p; p += 2304L * 768 * 2;
  unsigned short* w1T = (unsigned short*)p;   p += 3072L * 768 * 2;
  unsigned short* w2T = (unsigned short*)p;   p += 768L * 3072 * 2;
  unsigned short* qb = (unsigned short*)p;
  unsigned short* kb = qb + 6291456L;
  unsigned short* vt = kb + 6291456L;
  unsigned short* gbuf = qb;  // MLP hidden reuses q/k/v region

  hipMemcpyAsync(xw, x_in, 8192L * 768 * 4, hipMemcpyDeviceToDevice, stream);

  transpose_f2b_tiled<<<(768 * 768 / 8 + 255) / 256, 256, 0, stream>>>(
      wq, wqkvT, 768, 768);
  transpose_f2b_tiled<<<(768 * 768 / 8 + 255) / 256, 256, 0, stream>>>(
      wk, wqkvT + 768L * 768, 768, 768);
  transpose_f2b_tiled<<<(768 * 768 / 8 + 255) / 256, 256, 0, stream>>>(
      wv, wqkvT + 2L * 768 * 768, 768, 768);
  transpose_f2b_tiled<<<(768 * 3072 / 8 + 255) / 256, 256, 0, stream>>>(
      w1, w1T, 768, 3072);
  transpose_f2b_tiled<<<(768 * 3072 / 8 + 255) / 256, 256, 0, stream>>>(
      w2, w2T, 3072, 768);

  for (int layer = 0; layer < 12; ++layer) {
    ln_kernel<<<2048, 256, 0, stream>>>(xw, ln_w, ln_b, hbuf);
    // QKV in the BM=64 geometry (R12-proven for MLP1): supertile 9bx x 32by
    // (B-panel 1.8 MB L2-resident per XCD), 2304 blocks = 3 perfect rounds.
    gemm_bt<EPI_QKV, 2, 9, 32><<<dim3(18, 128), 256, 0, stream>>>(
        hbuf, wqkvT, 768, bq, bk, bv, qb, kb, vt, nullptr, nullptr);
    attn_kernel<<<dim3(4, 12, 16), 256, 0, stream>>>(qb, kb, vt, xw);
    ln_kernel<<<2048, 256, 0, stream>>>(xw, ln_w, ln_b, hbuf);
    // supertile sets 12bx x 32by (footprint ~2.4 MB B-panel/XCD)
    gemm_bt<EPI_GELU, 2, 12, 32><<<dim3(24, 128), 256, 0, stream>>>(
        hbuf, w1T, 768, b1, nullptr, nullptr, gbuf, nullptr, nullptr, nullptr,
        nullptr);
    gemm_bt<EPI_RES, 2, 0, 0><<<dim3(6, 128), 256, 0, stream>>>(
        gbuf, w2T, 3072, b2, nullptr, nullptr, nullptr, nullptr, nullptr, xw,
        layer == 11 ? (float*)d_out : xw);
  }
}